// Round 7
// baseline (205.483 us; speedup 1.0000x reference)
//
#include <hip/hip_runtime.h>
#include <math.h>

#define DIM 1024
#define DEPTH 7
#define PAR 8
#define N_NODES 255   // 2^(DEPTH+1) - 1
#define WIDTH 2040    // PAR * N_NODES
#define MARGIN 0.03f  // |logit| below this -> recompute dot in fp32 (decision safety)

typedef float  float2v  __attribute__((ext_vector_type(2)));
typedef _Float16 half2v __attribute__((ext_vector_type(2)));

__device__ __forceinline__ unsigned short f32_to_bf16(float f) {
    unsigned int u = __float_as_uint(f);
    u += 0x7fffu + ((u >> 16) & 1u);   // RTNE
    return (unsigned short)(u >> 16);
}
__device__ __forceinline__ float bf_lo(unsigned int u) { return __uint_as_float(u << 16); }
__device__ __forceinline__ float bf_hi(unsigned int u) { return __uint_as_float(u & 0xffff0000u); }

__device__ __forceinline__ half2v as_h2(unsigned int u) {
    union { unsigned int u; half2v h; } c; c.u = u; return c.h;
}
__device__ __forceinline__ unsigned int pack_h2(float a, float b) {
    union { half2v h; unsigned int u; } c;
    c.h = (half2v){(_Float16)a, (_Float16)b};   // v_cvt_f16_f32 is RTNE
    return c.u;
}

// f16 dot2 with fp32 accumulate
__device__ __forceinline__ float dot2h(unsigned int a, unsigned int b, float c) {
#if __has_builtin(__builtin_amdgcn_fdot2)
    return __builtin_amdgcn_fdot2(as_h2(a), as_h2(b), c, false);
#else
    half2v ha = as_h2(a), hb = as_h2(b);
    c = fmaf((float)ha.x, (float)hb.x, c);
    return fmaf((float)ha.y, (float)hb.y, c);
#endif
}

// fold two per-lane partial sums into one register, separated by lane bit K
__device__ __forceinline__ float foldK(float a, float b, int K) {
    const bool hi = (threadIdx.x & (unsigned)K) != 0;
    const float keep = hi ? b : a;
    const float send = hi ? a : b;
    return keep + __shfl_xor(send, K, 64);
}

// ---------------------------------------------------------------------------
// W_in f32 -> f16 packed (same [WIDTH][DIM] layout)
// ---------------------------------------------------------------------------
__global__ __launch_bounds__(256) void convert_f16_kernel(
    const float* __restrict__ src, unsigned int* __restrict__ dst, int n4)
{
    int i = (int)(blockIdx.x * blockDim.x + threadIdx.x);
    if (i < n4) {
        float4 v = ((const float4*)src)[i];
        uint2 pk;
        pk.x = pack_h2(v.x, v.y);
        pk.y = pack_h2(v.z, v.w);
        ((uint2*)dst)[i] = pk;
    }
}

// ---------------------------------------------------------------------------
// Transpose + convert: W_out f32 [DIM][WIDTH] -> WoT bf16 [WIDTH][DIM]
// ---------------------------------------------------------------------------
__global__ __launch_bounds__(256) void transpose_bf16_kernel(
    const float* __restrict__ W_out, unsigned short* __restrict__ WoT)
{
    __shared__ float tile[64][65];
    const int w0 = blockIdx.x * 64;
    const int d0 = blockIdx.y * 64;
    const int tid = (int)threadIdx.x;
    const int sub = tid & 15;
    const int grp = tid >> 4;

    #pragma unroll
    for (int pass = 0; pass < 4; ++pass) {
        const int dl = pass * 16 + grp;
        const int wl = sub * 4;
        const int w = w0 + wl;
        const int d = d0 + dl;
        float4 v = make_float4(0.f, 0.f, 0.f, 0.f);
        if (w + 3 < WIDTH) {
            v = *(const float4*)(W_out + (size_t)d * WIDTH + w);
        } else {
            float t0 = (w + 0 < WIDTH) ? W_out[(size_t)d * WIDTH + w + 0] : 0.f;
            float t1 = (w + 1 < WIDTH) ? W_out[(size_t)d * WIDTH + w + 1] : 0.f;
            float t2 = (w + 2 < WIDTH) ? W_out[(size_t)d * WIDTH + w + 2] : 0.f;
            float t3 = (w + 3 < WIDTH) ? W_out[(size_t)d * WIDTH + w + 3] : 0.f;
            v = make_float4(t0, t1, t2, t3);
        }
        tile[dl][wl + 0] = v.x; tile[dl][wl + 1] = v.y;
        tile[dl][wl + 2] = v.z; tile[dl][wl + 3] = v.w;
    }
    __syncthreads();
    #pragma unroll
    for (int pass = 0; pass < 4; ++pass) {
        const int wl = pass * 16 + grp;
        const int dl = sub * 4;
        const int w = w0 + wl;
        if (w < WIDTH) {
            unsigned int b0 = f32_to_bf16(tile[dl + 0][wl]);
            unsigned int b1 = f32_to_bf16(tile[dl + 1][wl]);
            unsigned int b2 = f32_to_bf16(tile[dl + 2][wl]);
            unsigned int b3 = f32_to_bf16(tile[dl + 3][wl]);
            uint2 pk;
            pk.x = b0 | (b1 << 16);
            pk.y = b2 | (b3 << 16);
            *(uint2*)(WoT + (size_t)w * DIM + d0 + dl) = pk;
        }
    }
}

// ---------------------------------------------------------------------------
// Main kernel: ONE BLOCK PER ROW, 4 waves x 2 trees each. Each wave is
// self-sufficient for its 2 trees (dots over its own 64 lanes, fold by lane
// bit 32, own ballot for decisions); per-level load count is 1/4 of the
// single-wave version, latency hidden by 4x wave oversubscription (TLP the
// compiler cannot undo). Final output combined via LDS.
// ---------------------------------------------------------------------------
__global__ __launch_bounds__(256) void fff_split_kernel(
    const float* __restrict__ x,            // [B, DIM] f32
    const float* __restrict__ W_in,         // [WIDTH, DIM] f32 (repair only)
    const float* __restrict__ b_in,         // [WIDTH] f32
    const unsigned int* __restrict__ Wh,    // f16 W_in  [WIDTH][DIM/2] dwords
    const unsigned short* __restrict__ WoT, // bf16 W_out^T [WIDTH][DIM]
    float* __restrict__ out,                // [B, DIM] f32
    int B)
{
    __shared__ float red[4][DIM];           // 16 KB
    const int row  = (int)blockIdx.x;
    if (row >= B) return;
    const int wv   = (int)(threadIdx.x >> 6);   // 0..3
    const int lane = (int)(threadIdx.x & 63);
    const int e0   = lane * 16;                 // this lane's 16 elements

    const float* xr = x + (size_t)row * DIM;
    unsigned int xp[8];
    {
        float4 a0 = *(const float4*)(xr + e0 + 0);
        float4 a1 = *(const float4*)(xr + e0 + 4);
        float4 a2 = *(const float4*)(xr + e0 + 8);
        float4 a3 = *(const float4*)(xr + e0 + 12);
        xp[0] = pack_h2(a0.x, a0.y); xp[1] = pack_h2(a0.z, a0.w);
        xp[2] = pack_h2(a1.x, a1.y); xp[3] = pack_h2(a1.z, a1.w);
        xp[4] = pack_h2(a2.x, a2.y); xp[5] = pack_h2(a2.z, a2.w);
        xp[6] = pack_h2(a3.x, a3.y); xp[7] = pack_h2(a3.z, a3.w);
    }

    float2v acc2[8];
    #pragma unroll
    for (int i = 0; i < 8; ++i) acc2[i] = (float2v){0.f, 0.f};

    const int t0 = 2 * wv, t1 = 2 * wv + 1;   // this wave's trees
    int n0 = 0, n1 = 0;

    #pragma unroll 1
    for (int d = 0; d <= DEPTH; ++d) {
        const int g0 = t0 * N_NODES + n0;
        const int g1 = t1 * N_NODES + n1;

        // stage-1 f16 loads for both trees (4 dwordx4 in flight)
        const unsigned int* wr0 = Wh + (size_t)g0 * (DIM / 2) + lane * 8;
        const unsigned int* wr1 = Wh + (size_t)g1 * (DIM / 2) + lane * 8;
        const uint4 ua = *(const uint4*)(wr0 + 0);
        const uint4 ub = *(const uint4*)(wr0 + 4);
        const uint4 va = *(const uint4*)(wr1 + 0);
        const uint4 vb = *(const uint4*)(wr1 + 4);

        float pa = 0.f, pb = 0.f;
        pa = dot2h(xp[0], ua.x, pa); pb = dot2h(xp[0], va.x, pb);
        pa = dot2h(xp[1], ua.y, pa); pb = dot2h(xp[1], va.y, pb);
        pa = dot2h(xp[2], ua.z, pa); pb = dot2h(xp[2], va.z, pb);
        pa = dot2h(xp[3], ua.w, pa); pb = dot2h(xp[3], va.w, pb);
        pa = dot2h(xp[4], ub.x, pa); pb = dot2h(xp[4], vb.x, pb);
        pa = dot2h(xp[5], ub.y, pa); pb = dot2h(xp[5], vb.y, pb);
        pa = dot2h(xp[6], ub.z, pa); pb = dot2h(xp[6], vb.z, pb);
        pa = dot2h(xp[7], ub.w, pa); pb = dot2h(xp[7], vb.w, pb);

        // fold tree0/tree1 onto lane bit 32, butterfly the rest
        float e = foldK(pa, pb, 32);
        e += __shfl_xor(e, 1, 64);
        e += __shfl_xor(e, 2, 64);
        e += __shfl_xor(e, 4, 64);
        e += __shfl_xor(e, 8, 64);
        e += __shfl_xor(e, 16, 64);

        const int gmine = (lane & 32) ? g1 : g0;
        float my = e + b_in[gmine];

        // fp32 repair of near-zero logits (decisions must match numpy)
        if (d < DEPTH) {
            const unsigned long long bal = __ballot(fabsf(my) < MARGIN);
            if (bal & 0x100000001ULL) {
                const float4 fa = *(const float4*)(xr + e0 + 0);
                const float4 fb = *(const float4*)(xr + e0 + 4);
                const float4 fc = *(const float4*)(xr + e0 + 8);
                const float4 fd = *(const float4*)(xr + e0 + 12);
                #pragma unroll 1
                for (int t = 0; t < 2; ++t) {
                    if (!((bal >> (t * 32)) & 1ULL)) continue;
                    const int gi = t ? g1 : g0;
                    const float* wr = W_in + (size_t)gi * DIM + e0;
                    const float4 wa = *(const float4*)(wr + 0);
                    const float4 wb = *(const float4*)(wr + 4);
                    const float4 wc = *(const float4*)(wr + 8);
                    const float4 wd = *(const float4*)(wr + 12);
                    float s = 0.f;
                    s = fmaf(fa.x, wa.x, s); s = fmaf(fa.y, wa.y, s);
                    s = fmaf(fa.z, wa.z, s); s = fmaf(fa.w, wa.w, s);
                    s = fmaf(fb.x, wb.x, s); s = fmaf(fb.y, wb.y, s);
                    s = fmaf(fb.z, wb.z, s); s = fmaf(fb.w, wb.w, s);
                    s = fmaf(fc.x, wc.x, s); s = fmaf(fc.y, wc.y, s);
                    s = fmaf(fc.z, wc.z, s); s = fmaf(fc.w, wc.w, s);
                    s = fmaf(fd.x, wd.x, s); s = fmaf(fd.y, wd.y, s);
                    s = fmaf(fd.z, wd.z, s); s = fmaf(fd.w, wd.w, s);
                    #pragma unroll
                    for (int off = 32; off >= 1; off >>= 1)
                        s += __shfl_xor(s, off, 64);
                    const float lf = s + b_in[gi];
                    if (((lane >> 5) & 1) == t) my = lf;
                }
            }
        }

        // per-lane silu, one ballot for both trees' decisions
        const float act_mine = my / (1.0f + __expf(-my));
        const unsigned long long pos = __ballot(my > 0.0f);
        const float act0 = __shfl(act_mine, 0, 64);
        const float act1 = __shfl(act_mine, 32, 64);

        // stage-2 bf16 axpy (4 dwordx4)
        const unsigned short* wo0 = WoT + (size_t)g0 * DIM + e0;
        const unsigned short* wo1 = WoT + (size_t)g1 * DIM + e0;
        const uint4 c0 = *(const uint4*)(wo0 + 0);
        const uint4 c1 = *(const uint4*)(wo0 + 8);
        const uint4 k0 = *(const uint4*)(wo1 + 0);
        const uint4 k1 = *(const uint4*)(wo1 + 8);
        const float2v A0 = (float2v){act0, act0};
        const float2v A1 = (float2v){act1, act1};
        acc2[0] += A0 * (float2v){bf_lo(c0.x), bf_hi(c0.x)};
        acc2[1] += A0 * (float2v){bf_lo(c0.y), bf_hi(c0.y)};
        acc2[2] += A0 * (float2v){bf_lo(c0.z), bf_hi(c0.z)};
        acc2[3] += A0 * (float2v){bf_lo(c0.w), bf_hi(c0.w)};
        acc2[4] += A0 * (float2v){bf_lo(c1.x), bf_hi(c1.x)};
        acc2[5] += A0 * (float2v){bf_lo(c1.y), bf_hi(c1.y)};
        acc2[6] += A0 * (float2v){bf_lo(c1.z), bf_hi(c1.z)};
        acc2[7] += A0 * (float2v){bf_lo(c1.w), bf_hi(c1.w)};
        acc2[0] += A1 * (float2v){bf_lo(k0.x), bf_hi(k0.x)};
        acc2[1] += A1 * (float2v){bf_lo(k0.y), bf_hi(k0.y)};
        acc2[2] += A1 * (float2v){bf_lo(k0.z), bf_hi(k0.z)};
        acc2[3] += A1 * (float2v){bf_lo(k0.w), bf_hi(k0.w)};
        acc2[4] += A1 * (float2v){bf_lo(k1.x), bf_hi(k1.x)};
        acc2[5] += A1 * (float2v){bf_lo(k1.y), bf_hi(k1.y)};
        acc2[6] += A1 * (float2v){bf_lo(k1.z), bf_hi(k1.z)};
        acc2[7] += A1 * (float2v){bf_lo(k1.w), bf_hi(k1.w)};

        if (d < DEPTH) {
            n0 = 2 * n0 + 1 + (int)(pos & 1ULL);
            n1 = 2 * n1 + 1 + (int)((pos >> 32) & 1ULL);
        }
    }

    // combine the 4 waves' partial outputs via LDS
    float* myred = red[wv];
    *(float4*)(myred + e0 + 0)  = make_float4(acc2[0].x, acc2[0].y, acc2[1].x, acc2[1].y);
    *(float4*)(myred + e0 + 4)  = make_float4(acc2[2].x, acc2[2].y, acc2[3].x, acc2[3].y);
    *(float4*)(myred + e0 + 8)  = make_float4(acc2[4].x, acc2[4].y, acc2[5].x, acc2[5].y);
    *(float4*)(myred + e0 + 12) = make_float4(acc2[6].x, acc2[6].y, acc2[7].x, acc2[7].y);
    __syncthreads();

    const int t = (int)threadIdx.x;           // 0..255 -> elements 4t..4t+3
    const float4 s0 = *(const float4*)(&red[0][t * 4]);
    const float4 s1 = *(const float4*)(&red[1][t * 4]);
    const float4 s2 = *(const float4*)(&red[2][t * 4]);
    const float4 s3 = *(const float4*)(&red[3][t * 4]);
    float4 r;
    r.x = (s0.x + s1.x) + (s2.x + s3.x);
    r.y = (s0.y + s1.y) + (s2.y + s3.y);
    r.z = (s0.z + s1.z) + (s2.z + s3.z);
    r.w = (s0.w + s1.w) + (s2.w + s3.w);
    *(float4*)(out + (size_t)row * DIM + t * 4) = r;
}

// ---------------------------------------------------------------------------
// Fallback (no workspace): fp32 gather both stages. Correct but slow.
// ---------------------------------------------------------------------------
__global__ __launch_bounds__(256) void fff_fallback_kernel(
    const float* __restrict__ x, const float* __restrict__ W_in,
    const float* __restrict__ b_in, const float* __restrict__ W_out,
    float* __restrict__ out, int B)
{
    const int wave = (int)((blockIdx.x * blockDim.x + threadIdx.x) >> 6);
    const int lane = (int)(threadIdx.x & 63);
    if (wave >= B) return;

    const float* xr = x + (size_t)wave * DIM;
    float4 x4[4];
    x4[0] = *(const float4*)(xr + lane * 8 + 0);
    x4[1] = *(const float4*)(xr + lane * 8 + 4);
    x4[2] = *(const float4*)(xr + 512 + lane * 8 + 0);
    x4[3] = *(const float4*)(xr + 512 + lane * 8 + 4);

    float acc[16];
    #pragma unroll
    for (int i = 0; i < 16; ++i) acc[i] = 0.f;
    int node[PAR];
    #pragma unroll
    for (int p = 0; p < PAR; ++p) node[p] = 0;

    for (int d = 0; d <= DEPTH; ++d) {
        #pragma unroll
        for (int p = 0; p < PAR; ++p) {
            const int gidx = p * N_NODES + node[p];
            const float* wr = W_in + (size_t)gidx * DIM;
            const float4 wa = *(const float4*)(wr + lane * 8 + 0);
            const float4 wb = *(const float4*)(wr + lane * 8 + 4);
            const float4 wc = *(const float4*)(wr + 512 + lane * 8 + 0);
            const float4 wd = *(const float4*)(wr + 512 + lane * 8 + 4);
            float s = 0.f;
            s = fmaf(x4[0].x, wa.x, s); s = fmaf(x4[0].y, wa.y, s);
            s = fmaf(x4[0].z, wa.z, s); s = fmaf(x4[0].w, wa.w, s);
            s = fmaf(x4[1].x, wb.x, s); s = fmaf(x4[1].y, wb.y, s);
            s = fmaf(x4[1].z, wb.z, s); s = fmaf(x4[1].w, wb.w, s);
            s = fmaf(x4[2].x, wc.x, s); s = fmaf(x4[2].y, wc.y, s);
            s = fmaf(x4[2].z, wc.z, s); s = fmaf(x4[2].w, wc.w, s);
            s = fmaf(x4[3].x, wd.x, s); s = fmaf(x4[3].y, wd.y, s);
            s = fmaf(x4[3].z, wd.z, s); s = fmaf(x4[3].w, wd.w, s);
            #pragma unroll
            for (int off = 32; off >= 1; off >>= 1)
                s += __shfl_xor(s, off, 64);
            const float logit = s + b_in[gidx];
            const float act = logit / (1.0f + __expf(-logit));
            #pragma unroll
            for (int k = 0; k < 2; ++k) {
                #pragma unroll
                for (int j = 0; j < 8; ++j) {
                    const int e = k * 512 + lane * 8 + j;
                    acc[k * 8 + j] = fmaf(act, W_out[(size_t)e * WIDTH + gidx], acc[k * 8 + j]);
                }
            }
            node[p] = 2 * node[p] + 1 + ((logit > 0.0f) ? 1 : 0);
        }
    }

    float* orow = out + (size_t)wave * DIM;
    *(float4*)(orow + lane * 8 + 0)       = make_float4(acc[0],  acc[1],  acc[2],  acc[3]);
    *(float4*)(orow + lane * 8 + 4)       = make_float4(acc[4],  acc[5],  acc[6],  acc[7]);
    *(float4*)(orow + 512 + lane * 8 + 0) = make_float4(acc[8],  acc[9],  acc[10], acc[11]);
    *(float4*)(orow + 512 + lane * 8 + 4) = make_float4(acc[12], acc[13], acc[14], acc[15]);
}

extern "C" void kernel_launch(void* const* d_in, const int* in_sizes, int n_in,
                              void* d_out, int out_size, void* d_ws, size_t ws_size,
                              hipStream_t stream) {
    const float* oldx  = (const float*)d_in[0];
    const float* W_in  = (const float*)d_in[1];
    const float* b_in  = (const float*)d_in[2];
    const float* W_out = (const float*)d_in[3];
    float* out = (float*)d_out;

    const int B = in_sizes[0] / DIM;   // 8192 rows

    const size_t half = (size_t)WIDTH * DIM * sizeof(unsigned short);  // 4.18 MB
    const bool use_lp = (ws_size >= 2 * half) && (d_ws != nullptr);

    if (use_lp) {
        unsigned short* WoT = (unsigned short*)d_ws;
        unsigned int*   Wh  = (unsigned int*)((char*)d_ws + half);
        dim3 tg((WIDTH + 63) / 64, DIM / 64);
        transpose_bf16_kernel<<<tg, 256, 0, stream>>>(W_out, WoT);
        const int n4 = WIDTH * DIM / 4;
        convert_f16_kernel<<<(n4 + 255) / 256, 256, 0, stream>>>(W_in, Wh, n4);
        fff_split_kernel<<<B, 256, 0, stream>>>(oldx, W_in, b_in, Wh, WoT, out, B);
    } else {
        const int blocks = (B + 3) / 4;
        fff_fallback_kernel<<<blocks, 256, 0, stream>>>(oldx, W_in, b_in, W_out, out, B);
    }
}